// Round 5
// baseline (365.329 us; speedup 1.0000x reference)
//
#include <hip/hip_runtime.h>

// B=8, C=64, H=256, W=512, 3x3 spherical taps, O=1, 2x2 upsample -> (8,1,512,1024) fp32.
#define Bn   8
#define Cn   64
#define Hn   256
#define Wn   512
#define HWn  (Hn * Wn)
#define TAPS 9

typedef float vfloat2 __attribute__((ext_vector_type(2)));  // NT-compatible vectors
typedef float vfloat4 __attribute__((ext_vector_type(4)));

// ---------------------------------------------------------------------------
// Pass 1: channel-dot into planar D[k][b][p] = sum_c feat[b][c][p]*wt[c][k].
// Thread = (4 consecutive pixels, 1 batch): 64 float4 NT loads (16 B/lane),
// acc 9 x float4 (36 VGPRs). Double-buffered chunks of 4 channels (16 float4
// loads in flight). Grid = 262144 threads -> 16 waves/CU for latency hiding.
// Stores are fully-coalesced float4 full lines (regular stores -> L2/L3
// resident for pass2).
// ---------------------------------------------------------------------------
__global__ __launch_bounds__(256) void pass1_chandot(
    const float* __restrict__ feat, const float* __restrict__ wt,
    float* __restrict__ D)
{
    const int t = blockIdx.x * 256 + threadIdx.x;   // 0 .. 8*HW/4 - 1
    const int b = t >> 15;                          // HW/4 = 32768 threads/batch
    const int p = (t & 32767) << 2;                 // pixel quad

    const float* fb = feat + (size_t)b * (Cn * (size_t)HWn) + p;

    vfloat4 acc[TAPS];
#pragma unroll
    for (int k = 0; k < TAPS; ++k) acc[k] = (vfloat4)0.f;

    vfloat4 buf[2][4];
#pragma unroll
    for (int ci = 0; ci < 4; ++ci)
        buf[0][ci] = __builtin_nontemporal_load(
            (const vfloat4*)(fb + (size_t)ci * HWn));

#pragma unroll
    for (int g = 0; g < 16; ++g) {
        const int cur = g & 1, nxt = cur ^ 1;
        if (g < 15) {
            const int c0 = (g + 1) * 4;
#pragma unroll
            for (int ci = 0; ci < 4; ++ci)
                buf[nxt][ci] = __builtin_nontemporal_load(
                    (const vfloat4*)(fb + (size_t)(c0 + ci) * HWn));
        }
#pragma unroll
        for (int ci = 0; ci < 4; ++ci) {
            const int c = g * 4 + ci;
            const vfloat4 f = buf[cur][ci];
#pragma unroll
            for (int k = 0; k < TAPS; ++k) {
                const float wv = wt[c * TAPS + k];   // wave-uniform -> s_load
                acc[k] += f * wv;                    // contracts to v_fma
            }
        }
    }

#pragma unroll
    for (int k = 0; k < TAPS; ++k)
        *(vfloat4*)(D + (size_t)(k * Bn + b) * HWn + p) = acc[k];
}

// ---------------------------------------------------------------------------
// Pass 2: thread = (pixel, batch), px-major (wave = 32 px x 2 b).
// Block covers 32 pixels; their 288 gather offsets staged through LDS
// (coalesced global read; stride-9 LDS reads conflict-free, gcd(9,32)=1).
// 9 scalar gathers/thread from L2/L3-resident planar D (lanes' gj nearly
// consecutive -> few lines per wave-gather). NT-store the 2x2-upsampled out.
// Grid = 4096 blocks -> 16 waves/CU.
// ---------------------------------------------------------------------------
__global__ __launch_bounds__(256) void pass2_gather(
    const float* __restrict__ D, const int* __restrict__ gi,
    const int* __restrict__ gj, float* __restrict__ out)
{
    __shared__ int loff[32 * TAPS];
    const int tid = threadIdx.x;
    const int p0  = blockIdx.x * 32;

    for (int i = tid; i < 32 * TAPS; i += 256) {
        const int g = p0 * TAPS + i;
        loff[i] = gi[g] * Wn + gj[g];
    }
    __syncthreads();

    const int px = tid & 31;
    const int b  = tid >> 5;
    const int p  = p0 + px;
    const int w  = p & (Wn - 1);
    const int h  = p >> 9;

    float a = 0.f;
#pragma unroll
    for (int k = 0; k < TAPS; ++k) {
        const int off = loff[px * TAPS + k];
        a += D[(size_t)(k * Bn + b) * HWn + off];
    }

    vfloat2 vv = {a, a};
    const size_t o = ((size_t)b * (2 * Hn) + 2 * h) * (size_t)(2 * Wn) + 2 * w;
    __builtin_nontemporal_store(vv, (vfloat2*)(out + o));
    __builtin_nontemporal_store(vv, (vfloat2*)(out + o + 2 * Wn));
}

// ---------------------------------------------------------------------------
// Fallback (ws too small): direct per-pixel 9x64 gather-dot.
// ---------------------------------------------------------------------------
__global__ __launch_bounds__(256) void direct_kernel(
    const float* __restrict__ feat, const float* __restrict__ wt,
    const int* __restrict__ gi, const int* __restrict__ gj,
    float* __restrict__ out)
{
    int p = blockIdx.x * blockDim.x + threadIdx.x;
    int w = p & (Wn - 1);
    int h = (p >> 9) & (Hn - 1);
    int b = p >> 17;

    int iidx = ((h << 9) | w) * TAPS;
    int off[TAPS];
#pragma unroll
    for (int k = 0; k < TAPS; ++k)
        off[k] = gi[iidx + k] * Wn + gj[iidx + k];

    float acc = 0.f;
    for (int c = 0; c < Cn; ++c) {
        const float* fc = feat + ((size_t)b * Cn + c) * HWn;
#pragma unroll
        for (int k = 0; k < TAPS; ++k)
            acc = fmaf(fc[off[k]], wt[c * TAPS + k], acc);
    }

    float2 v = make_float2(acc, acc);
    size_t o0 = ((size_t)b * (2 * Hn) + 2 * h) * (size_t)(2 * Wn) + 2 * w;
    *(float2*)(out + o0)          = v;
    *(float2*)(out + o0 + 2 * Wn) = v;
}

extern "C" void kernel_launch(void* const* d_in, const int* in_sizes, int n_in,
                              void* d_out, int out_size, void* d_ws, size_t ws_size,
                              hipStream_t stream) {
    const float* feat = (const float*)d_in[0];   // [8,64,256,512] fp32
    const float* wt   = (const float*)d_in[1];   // [1,64,3,3]     fp32
    const int*   gi   = (const int*)d_in[2];     // [256,512,9]    int32
    const int*   gj   = (const int*)d_in[3];     // [256,512,9]    int32
    float*       out  = (float*)d_out;           // [8,1,512,1024] fp32

    const size_t bytesD = (size_t)TAPS * Bn * HWn * sizeof(float); // 37.75 MB

    if (ws_size >= bytesD) {
        float* D = (float*)d_ws;
        pass1_chandot<<<(Bn * HWn / 4) / 256, 256, 0, stream>>>(feat, wt, D);
        pass2_gather <<<HWn / 32,            256, 0, stream>>>(D, gi, gj, out);
    } else {
        direct_kernel<<<(Bn * HWn) / 256, 256, 0, stream>>>(feat, wt, gi, gj, out);
    }
}